// Round 5
// baseline (337.111 us; speedup 1.0000x reference)
//
#include <hip/hip_runtime.h>

// Problem: N=32, C=512, H=W=32 (HW=1024), D=256.
// out = x + W_fuse * softmax((Wt x)^T (Wp x) / 16) applied to values x, per batch.
//
// Pipeline (all bf16 MFMA, fp32 accumulate):
//  k_packw : W_theta|W_phi -> Wcat bf16 [512][512], W_fuse -> bf16 [512][512]
//  k_prep  : x [n,c,q] fp32 -> xt [n,q,c] bf16 (transposed, pixel-major)
//  k_embed : tp[n,q,0:256]=theta, [256:512]=phi  (GEMM 32768x512x512)
//  k_cast  : x fp32 -> xb bf16 [n,c,q] (native layout), overwrites xt space
//  k_attn5 : per (n, 32-query tile), 8 waves, round-3 2-barrier loop:
//            8 KV-tiles of 128 keys: S=Q K^T/16 (Q in LDS, K direct), P=exp(S)
//            -> LDS [32][136], PV accumulate (V=xb direct bf16).
//            q-tile 32 halves accO (32 AGPR) + LDS (33.3KB) vs round 3 ->
//            launch_bounds(512,6) targets 24 waves/CU (was 16).
//            Fuse conv with swapped operands (q = output row) -> float4 stores.
//
// Workspace (65 MB):
//   [0,32MB)    xt  (k_prep->k_embed), then xb (k_cast->k_attn5)
//   [32,64MB)   tp
//   [64MB,+512K)  Wcat bf16 ; [+512K,+1MB) Wfuse bf16

#define NB  32
#define CC  512
#define HWD 1024

typedef __attribute__((ext_vector_type(8))) short short8;
typedef __attribute__((ext_vector_type(4))) float f32x4;

__device__ __forceinline__ unsigned short f2bu(float f) {
    unsigned int u = __float_as_uint(f);
    u = (u + 0x7FFFu + ((u >> 16) & 1u)) >> 16;   // RNE to bf16
    return (unsigned short)u;
}

// ---------------- weights pack ----------------
__global__ __launch_bounds__(256) void k_packw(const float* __restrict__ Wt,
                                               const float* __restrict__ Wp,
                                               const float* __restrict__ Wf,
                                               unsigned short* __restrict__ Wcat,
                                               unsigned short* __restrict__ Wfuse) {
    int idx = blockIdx.x * 256 + threadIdx.x;       // 0 .. 262143
    int o = idx >> 9;
    float cv = (o < 256) ? Wt[idx] : Wp[idx - 131072];
    Wcat[idx]  = f2bu(cv);
    Wfuse[idx] = f2bu(Wf[idx]);
}

// ---------------- x transpose -> xt[n,q,c] bf16 ----------------
__global__ __launch_bounds__(256) void k_prep(const float* __restrict__ x,
                                              unsigned short* __restrict__ xt) {
    __shared__ float tile[32][33];
    const int n = blockIdx.z, c0 = blockIdx.y << 5, q0 = blockIdx.x << 5;
    const int t = threadIdx.x;
    const int r = t >> 3, j4 = (t & 7) << 2;
    const float* src = x + ((size_t)(n * CC + c0 + r)) * HWD + q0 + j4;
    float4 v = *(const float4*)src;
    tile[r][j4 + 0] = v.x; tile[r][j4 + 1] = v.y;
    tile[r][j4 + 2] = v.z; tile[r][j4 + 3] = v.w;
    __syncthreads();
    ushort4 uv;
    uv.x = f2bu(tile[j4 + 0][r]);
    uv.y = f2bu(tile[j4 + 1][r]);
    uv.z = f2bu(tile[j4 + 2][r]);
    uv.w = f2bu(tile[j4 + 3][r]);
    *(ushort4*)(xt + ((size_t)(n * HWD + q0 + r)) * CC + c0 + j4) = uv;
}

// ---------------- x -> xb bf16 (same layout) ----------------
__global__ __launch_bounds__(256) void k_cast(const float* __restrict__ x,
                                              unsigned short* __restrict__ xb) {
    const size_t i = ((size_t)blockIdx.x * 256 + threadIdx.x) * 8;
    float4 v0 = *(const float4*)(x + i);
    float4 v1 = *(const float4*)(x + i + 4);
    short8 o;
    o[0] = (short)f2bu(v0.x); o[1] = (short)f2bu(v0.y);
    o[2] = (short)f2bu(v0.z); o[3] = (short)f2bu(v0.w);
    o[4] = (short)f2bu(v1.x); o[5] = (short)f2bu(v1.y);
    o[6] = (short)f2bu(v1.z); o[7] = (short)f2bu(v1.w);
    *(short8*)(xb + i) = o;
}

// ---------------- embed GEMM: tp = xt * Wcat^T + bias ----------------
__global__ __launch_bounds__(256) void k_embed(const unsigned short* __restrict__ xt,
                                               const unsigned short* __restrict__ Wcat,
                                               const float* __restrict__ bt,
                                               const float* __restrict__ bp,
                                               unsigned short* __restrict__ tp) {
    __shared__ __align__(16) unsigned short As[128 * 40];
    __shared__ __align__(16) unsigned short Bs[128 * 40];
    const int m0 = blockIdx.x << 7, n0 = blockIdx.y << 7;
    const int t = threadIdx.x, lane = t & 63, wave = t >> 6;
    const int wr = wave >> 1, wc = wave & 1;
    const int lrow = lane & 15, hi = lane >> 4, lhk = hi << 3;
    const f32x4 fz = {0.f, 0.f, 0.f, 0.f};
    f32x4 acc[4][4];
#pragma unroll
    for (int i = 0; i < 4; ++i)
#pragma unroll
        for (int j = 0; j < 4; ++j) acc[i][j] = fz;

    for (int kt = 0; kt < 16; ++kt) {
        const int k0 = kt << 5;
#pragma unroll
        for (int i = 0; i < 2; ++i) {
            int chunk = t + (i << 8);
            int r = chunk >> 2, ko = (chunk & 3) << 3;
            *(uint4*)(As + r * 40 + ko) =
                *(const uint4*)(xt + ((size_t)(m0 + r)) * CC + k0 + ko);
            *(uint4*)(Bs + r * 40 + ko) =
                *(const uint4*)(Wcat + ((size_t)(n0 + r)) * CC + k0 + ko);
        }
        __syncthreads();
        short8 af[4], bfm[4];
#pragma unroll
        for (int mi = 0; mi < 4; ++mi)
            af[mi] = *(const short8*)(As + (wr * 64 + mi * 16 + lrow) * 40 + lhk);
#pragma unroll
        for (int ni = 0; ni < 4; ++ni)
            bfm[ni] = *(const short8*)(Bs + (wc * 64 + ni * 16 + lrow) * 40 + lhk);
#pragma unroll
        for (int mi = 0; mi < 4; ++mi)
#pragma unroll
            for (int ni = 0; ni < 4; ++ni)
                acc[mi][ni] = __builtin_amdgcn_mfma_f32_16x16x32_bf16(
                    af[mi], bfm[ni], acc[mi][ni], 0, 0, 0);
        __syncthreads();
    }
#pragma unroll
    for (int ni = 0; ni < 4; ++ni) {
        const int col = n0 + wc * 64 + ni * 16 + lrow;
        const float bias = (col < 256) ? bt[col] : bp[col - 256];
#pragma unroll
        for (int mi = 0; mi < 4; ++mi)
#pragma unroll
            for (int j = 0; j < 4; ++j) {
                const int row = m0 + wr * 64 + mi * 16 + hi * 4 + j;
                tp[(size_t)row * CC + col] = f2bu(acc[mi][ni][j] + bias);
            }
    }
}

// ---------------- flash attention + fuse conv + residual ----------------
// 8 waves, 32-query tile, KV tiles of 128 keys (wave k-slot 16, c-slot 64).
__global__ __launch_bounds__(512, 6) void k_attn5(const unsigned short* __restrict__ tp,
                                                  const unsigned short* __restrict__ xb,
                                                  const unsigned short* __restrict__ Wfuse,
                                                  const float* __restrict__ bfu,
                                                  const float* __restrict__ x,
                                                  float* __restrict__ out) {
    constexpr int QST = 264;                       // Q row stride (bf16)
    constexpr int PST = 136;                       // P row stride (bf16)
    constexpr int OST = 520;                       // Os row stride (bf16)
    constexpr int QSZ = 32 * QST;                  // 8448 elems
    __shared__ __align__(16) unsigned short SL[32 * OST];   // 33,280 B (>= Q+P)
    __shared__ float rowsum[32];
    unsigned short* Qs = SL;                       // [32][264]
    unsigned short* P  = SL + QSZ;                 // [32][136]
    unsigned short* Os = SL;                       // overlay [32][520]

    const int n = blockIdx.x, q0 = blockIdx.y << 5;   // XCD = n % 8
    const int t = threadIdx.x, lane = t & 63, wave = t >> 6;
    const int lrow = lane & 15, hi = lane >> 4, lhk = hi << 3;
    const f32x4 fz = {0.f, 0.f, 0.f, 0.f};

    const unsigned short* tpn = tp + (size_t)n * HWD * CC;
    const unsigned short* xbn = xb + (size_t)n * CC * HWD;

    if (t < 32) rowsum[t] = 0.f;
    // stage Q tile: rows q0..q0+31, d 0..255 (1024 short8 loads, 2/thread)
#pragma unroll
    for (int pass = 0; pass < 2; ++pass) {
        int chunk = (pass << 9) + t;               // 0..1023
        int row = chunk >> 5, co = (chunk & 31) << 3;
        *(short8*)(Qs + row * QST + co) =
            *(const short8*)(tpn + (size_t)(q0 + row) * CC + co);
    }
    __syncthreads();

    f32x4 accO[2][4];
#pragma unroll
    for (int qj = 0; qj < 2; ++qj)
#pragma unroll
        for (int ci = 0; ci < 4; ++ci) accO[qj][ci] = fz;
    float psum[2][4] = {{0.f, 0.f, 0.f, 0.f}, {0.f, 0.f, 0.f, 0.f}};

    const int kw = wave << 4;                      // wave's 16-key slot in tile
    const int cw = wave << 6;                      // wave's 64-channel range

    for (int it = 0; it < 8; ++it) {
        const int kv0 = it << 7;                   // KV tile base (128 keys)
        // ---- S = Q K^T / 16, P = exp(S) ----
        f32x4 accA[2];
        accA[0] = fz; accA[1] = fz;
#pragma unroll
        for (int kt = 0; kt < 8; ++kt) {
            const int d0 = (kt << 5) + lhk;
            short8 kfr = *(const short8*)(tpn + (size_t)(kv0 + kw + lrow) * CC + 256 + d0);
#pragma unroll
            for (int qj = 0; qj < 2; ++qj) {
                short8 qfr = *(const short8*)(Qs + (qj * 16 + lrow) * QST + d0);
                accA[qj] = __builtin_amdgcn_mfma_f32_16x16x32_bf16(qfr, kfr, accA[qj], 0, 0, 0);
            }
        }
#pragma unroll
        for (int qj = 0; qj < 2; ++qj)
#pragma unroll
            for (int j = 0; j < 4; ++j) {
                float p = __expf(accA[qj][j] * 0.0625f);
                psum[qj][j] += p;
                P[(qj * 16 + hi * 4 + j) * PST + kw + lrow] = f2bu(p);
            }
        __syncthreads();
        // ---- O += P V^T ----
        __builtin_amdgcn_s_setprio(1);
#pragma unroll
        for (int ks = 0; ks < 4; ++ks) {
            const int kb = (ks << 5) + lhk;
            short8 pa[2];
#pragma unroll
            for (int qj = 0; qj < 2; ++qj)
                pa[qj] = *(const short8*)(P + (qj * 16 + lrow) * PST + kb);
#pragma unroll
            for (int ci = 0; ci < 4; ++ci) {
                short8 vf = *(const short8*)(xbn + (size_t)(cw + ci * 16 + lrow) * HWD + kv0 + kb);
#pragma unroll
                for (int qj = 0; qj < 2; ++qj)
                    accO[qj][ci] = __builtin_amdgcn_mfma_f32_16x16x32_bf16(pa[qj], vf, accO[qj][ci], 0, 0, 0);
            }
        }
        __builtin_amdgcn_s_setprio(0);
        __syncthreads();
    }

    // ---- row sums across waves ----
#pragma unroll
    for (int qj = 0; qj < 2; ++qj)
#pragma unroll
        for (int j = 0; j < 4; ++j) {
            float s = psum[qj][j];
            s += __shfl_xor(s, 1, 16);
            s += __shfl_xor(s, 2, 16);
            s += __shfl_xor(s, 4, 16);
            s += __shfl_xor(s, 8, 16);
            if (lrow == 0) atomicAdd(&rowsum[qj * 16 + hi * 4 + j], s);
        }
    __syncthreads();                               // rowsum done; Q/P reads done

    // ---- normalize -> Os (overlays Q/P) ----
#pragma unroll
    for (int qj = 0; qj < 2; ++qj) {
#pragma unroll
        for (int j = 0; j < 4; ++j) {
            const float inv = 1.f / rowsum[qj * 16 + hi * 4 + j];
#pragma unroll
            for (int ci = 0; ci < 4; ++ci)
                Os[(qj * 16 + hi * 4 + j) * OST + cw + (ci << 4) + lrow] =
                    f2bu(accO[qj][ci][j] * inv);
        }
    }
    __syncthreads();

    // ---- fuse conv (swapped operands: q = output row) ----
    // accF[mi][qj]: rows = q (hi*4+j consecutive), cols = o (lrow)
    f32x4 accF[4][2];
#pragma unroll
    for (int mi = 0; mi < 4; ++mi) { accF[mi][0] = fz; accF[mi][1] = fz; }
    const int ob = wave << 6;                      // wave's 64-output range
    for (int kt = 0; kt < 16; ++kt) {
        const int k0 = (kt << 5) + lhk;
        short8 bq[2];
#pragma unroll
        for (int qj = 0; qj < 2; ++qj)
            bq[qj] = *(const short8*)(Os + (qj * 16 + lrow) * OST + k0);
        __builtin_amdgcn_s_setprio(1);
#pragma unroll
        for (int mi = 0; mi < 4; ++mi) {
            short8 af = *(const short8*)(Wfuse + (size_t)(ob + (mi << 4) + lrow) * CC + k0);
#pragma unroll
            for (int qj = 0; qj < 2; ++qj)
                accF[mi][qj] = __builtin_amdgcn_mfma_f32_16x16x32_bf16(bq[qj], af, accF[mi][qj], 0, 0, 0);
        }
        __builtin_amdgcn_s_setprio(0);
    }
    // lane (lrow,hi) holds q = q0 + qj*16 + hi*4 + (0..3) for o = ob + mi*16 + lrow
#pragma unroll
    for (int mi = 0; mi < 4; ++mi) {
        const int o = ob + (mi << 4) + lrow;
        const float bias = bfu[o];
#pragma unroll
        for (int qj = 0; qj < 2; ++qj) {
            const size_t idx = ((size_t)(n * CC + o)) * HWD + q0 + qj * 16 + (hi << 2);
            const float4 xr = *(const float4*)(x + idx);
            float4 r;
            r.x = accF[mi][qj][0] + bias + xr.x;
            r.y = accF[mi][qj][1] + bias + xr.y;
            r.z = accF[mi][qj][2] + bias + xr.z;
            r.w = accF[mi][qj][3] + bias + xr.w;
            *(float4*)(out + idx) = r;
        }
    }
}

extern "C" void kernel_launch(void* const* d_in, const int* in_sizes, int n_in,
                              void* d_out, int out_size, void* d_ws, size_t ws_size,
                              hipStream_t stream) {
    const float* x  = (const float*)d_in[0];
    const float* Wt = (const float*)d_in[1];
    const float* bt = (const float*)d_in[2];
    const float* Wp = (const float*)d_in[3];
    const float* bp = (const float*)d_in[4];
    const float* Wf = (const float*)d_in[5];
    const float* bfu = (const float*)d_in[6];
    float* out = (float*)d_out;

    char* ws = (char*)d_ws;
    unsigned short* xt_xb = (unsigned short*)(ws);                 // 32 MB (xt, later xb)
    unsigned short* tp    = (unsigned short*)(ws + 33554432);      // 32 MB
    unsigned short* Wcat  = (unsigned short*)(ws + 67108864);      // 512 KB
    unsigned short* Wfuse = (unsigned short*)(ws + 67633152);      // 512 KB

    k_packw<<<dim3(1024), 256, 0, stream>>>(Wt, Wp, Wf, Wcat, Wfuse);
    k_prep <<<dim3(32, 16, 32), 256, 0, stream>>>(x, xt_xb);
    k_embed<<<dim3(256, 4), 256, 0, stream>>>(xt_xb, Wcat, bt, bp, tp);
    k_cast <<<dim3(8192), 256, 0, stream>>>(x, xt_xb);             // xb overwrites xt
    k_attn5<<<dim3(32, 32), 512, 0, stream>>>(tp, xt_xb, Wfuse, bfu, x, out);
}

// Round 6
// 195.357 us; speedup vs baseline: 1.7256x; 1.7256x over previous
//
#include <hip/hip_runtime.h>

// Problem: N=32, C=512, H=W=32 (HW=1024), D=256.
// out = x + W_fuse * softmax((Wt x)^T (Wp x) / 16) applied to values x, per batch.
//
// Key identity: out = x + b_fuse + (Z P^T)/rowsum, where Z = W_fuse * V  (per batch,
// V = x[n,c,k]), P = exp(Q K^T/16). Z is query-independent -> precompute as a GEMM.
//
// Pipeline (all bf16 MFMA, fp32 accumulate):
//  k_packw  : W_theta|W_phi -> Wcat bf16 [512][512], W_fuse -> bf16 [512][512]
//  k_embed2 : tp[n,q,0:256]=theta, [256:512]=phi. Pixel A-tiles transpose-staged
//             in-kernel from fp32 x (no xt buffer). N-tile 256 (2 octiles).
//  k_zgemm  : Z[n,o,k] = sum_c Wf[o,c] x[n,c,k] (same structure; A=pixels, B=Wfuse)
//  k_attn6  : per (n, 64-query tile), 8 waves, 4 iters of 256 keys:
//             S = Q K^T/16 (Q in LDS, K direct), P=exp(S)->LDS[64][264],
//             psum->rowsum (LDS atomics, per iter), barrier,
//             accF += Z . P (Z direct loads, P from LDS), barrier.
//             Epilogue: out[n,o,q] = x + b_fuse[o] + accF/rowsum[q].
//
// Workspace (65 MB): [0,32MB) tp ; [32,64MB) Z ; [64MB,+512K) Wcat ; [+512K,+1MB) Wfuse

#define NB  32
#define CC  512
#define HWD 1024

typedef __attribute__((ext_vector_type(8))) short short8;
typedef __attribute__((ext_vector_type(4))) float f32x4;

__device__ __forceinline__ unsigned short f2bu(float f) {
    unsigned int u = __float_as_uint(f);
    u = (u + 0x7FFFu + ((u >> 16) & 1u)) >> 16;   // RNE to bf16
    return (unsigned short)u;
}

// ---------------- weights pack ----------------
__global__ __launch_bounds__(256) void k_packw(const float* __restrict__ Wt,
                                               const float* __restrict__ Wp,
                                               const float* __restrict__ Wf,
                                               unsigned short* __restrict__ Wcat,
                                               unsigned short* __restrict__ Wfuse) {
    int idx = blockIdx.x * 256 + threadIdx.x;       // 0 .. 262143
    int o = idx >> 9;
    float cv = (o < 256) ? Wt[idx] : Wp[idx - 131072];
    Wcat[idx]  = f2bu(cv);
    Wfuse[idx] = f2bu(Wf[idx]);
}

// ---------------- embed GEMM: tp[pix][oc] = pix . Wcat^T + bias ----------------
// 512 threads, M-tile 128 pixels (transpose-staged from x), N-tile 256 weights.
__global__ __launch_bounds__(512) void k_embed2(const float* __restrict__ x,
                                                const unsigned short* __restrict__ Wcat,
                                                const float* __restrict__ bt,
                                                const float* __restrict__ bp,
                                                unsigned short* __restrict__ tp) {
    __shared__ __align__(16) float Tr[32 * 132];                 // 16896 B
    __shared__ __align__(16) unsigned short As[128 * 40];        // 10240 B
    __shared__ __align__(16) unsigned short Bs[256 * 40];        // 20480 B
    const int m0 = blockIdx.x << 7;                // global pixel row base
    const int n0 = blockIdx.y << 8;                // weight-col base (0 or 256)
    const int n  = m0 >> 10, qbase = m0 & 1023;
    const int t = threadIdx.x, lane = t & 63, wave = t >> 6;
    const int wr = wave >> 2, wc = wave & 3;
    const int lrow = lane & 15, hi = lane >> 4, lhk = hi << 3;
    const f32x4 fz = {0.f, 0.f, 0.f, 0.f};
    f32x4 acc[4][4];
#pragma unroll
    for (int i = 0; i < 4; ++i)
#pragma unroll
        for (int j = 0; j < 4; ++j) acc[i][j] = fz;

    const int tr_r = t >> 4, tr_q = (t & 15) << 3;        // Tr stage: 32 rows x 128 f32
    const int p2_pix = t & 127, p2_c = (t >> 7) << 3;     // transpose: pix, c-group

    for (int kt = 0; kt < 16; ++kt) {
        const int k0 = kt << 5;
        // phase 1: x[c-slice][pix-range] -> Tr (fp32), Wcat -> Bs
        {
            const float* src = x + ((size_t)(n * CC + k0 + tr_r)) * HWD + qbase + tr_q;
            float4 v0 = *(const float4*)(src);
            float4 v1 = *(const float4*)(src + 4);
            *(float4*)(Tr + tr_r * 132 + tr_q) = v0;
            *(float4*)(Tr + tr_r * 132 + tr_q + 4) = v1;
#pragma unroll
            for (int i = 0; i < 2; ++i) {
                int chunk = t + (i << 9);
                int r = chunk >> 2, ko = (chunk & 3) << 3;
                *(uint4*)(Bs + r * 40 + ko) =
                    *(const uint4*)(Wcat + ((size_t)(n0 + r)) * CC + k0 + ko);
            }
        }
        __syncthreads();
        // phase 2: Tr -> As (bf16, transposed)
        {
            short8 o8;
#pragma unroll
            for (int j = 0; j < 8; ++j)
                o8[j] = (short)f2bu(Tr[(p2_c + j) * 132 + p2_pix]);
            *(short8*)(As + p2_pix * 40 + p2_c) = o8;
        }
        __syncthreads();
        short8 af[4], bfm[4];
#pragma unroll
        for (int mi = 0; mi < 4; ++mi)
            af[mi] = *(const short8*)(As + (wr * 64 + mi * 16 + lrow) * 40 + lhk);
#pragma unroll
        for (int ni = 0; ni < 4; ++ni)
            bfm[ni] = *(const short8*)(Bs + (wc * 64 + ni * 16 + lrow) * 40 + lhk);
#pragma unroll
        for (int mi = 0; mi < 4; ++mi)
#pragma unroll
            for (int ni = 0; ni < 4; ++ni)
                acc[mi][ni] = __builtin_amdgcn_mfma_f32_16x16x32_bf16(
                    af[mi], bfm[ni], acc[mi][ni], 0, 0, 0);
        __syncthreads();
    }
#pragma unroll
    for (int ni = 0; ni < 4; ++ni) {
        const int col = n0 + wc * 64 + ni * 16 + lrow;
        const float bias = (col < 256) ? bt[col] : bp[col - 256];
#pragma unroll
        for (int mi = 0; mi < 4; ++mi)
#pragma unroll
            for (int j = 0; j < 4; ++j) {
                const int row = m0 + wr * 64 + mi * 16 + hi * 4 + j;
                tp[(size_t)row * CC + col] = f2bu(acc[mi][ni][j] + bias);
            }
    }
}

// ---------------- Z GEMM: Z[n][o][k] = sum_c Wf[o,c] x[n,c,k] ----------------
// A = pixel tile (transpose-staged), B = Wfuse (N-tile 256). acc row=pix, col=o.
__global__ __launch_bounds__(512) void k_zgemm(const float* __restrict__ x,
                                               const unsigned short* __restrict__ Wfuse,
                                               unsigned short* __restrict__ Z) {
    __shared__ __align__(16) float Tr[32 * 132];
    __shared__ __align__(16) unsigned short As[128 * 40];
    __shared__ __align__(16) unsigned short Bs[256 * 40];
    const int m0 = blockIdx.x << 7;                // global pixel row base
    const int n0 = blockIdx.y << 8;                // o base (0 or 256)
    const int n  = m0 >> 10, qbase = m0 & 1023;
    const int t = threadIdx.x, lane = t & 63, wave = t >> 6;
    const int wr = wave >> 2, wc = wave & 3;
    const int lrow = lane & 15, hi = lane >> 4, lhk = hi << 3;
    const f32x4 fz = {0.f, 0.f, 0.f, 0.f};
    f32x4 acc[4][4];
#pragma unroll
    for (int i = 0; i < 4; ++i)
#pragma unroll
        for (int j = 0; j < 4; ++j) acc[i][j] = fz;

    const int tr_r = t >> 4, tr_q = (t & 15) << 3;
    const int p2_pix = t & 127, p2_c = (t >> 7) << 3;

    for (int kt = 0; kt < 16; ++kt) {
        const int k0 = kt << 5;
        {
            const float* src = x + ((size_t)(n * CC + k0 + tr_r)) * HWD + qbase + tr_q;
            float4 v0 = *(const float4*)(src);
            float4 v1 = *(const float4*)(src + 4);
            *(float4*)(Tr + tr_r * 132 + tr_q) = v0;
            *(float4*)(Tr + tr_r * 132 + tr_q + 4) = v1;
#pragma unroll
            for (int i = 0; i < 2; ++i) {
                int chunk = t + (i << 9);
                int r = chunk >> 2, ko = (chunk & 3) << 3;
                *(uint4*)(Bs + r * 40 + ko) =
                    *(const uint4*)(Wfuse + ((size_t)(n0 + r)) * CC + k0 + ko);
            }
        }
        __syncthreads();
        {
            short8 o8;
#pragma unroll
            for (int j = 0; j < 8; ++j)
                o8[j] = (short)f2bu(Tr[(p2_c + j) * 132 + p2_pix]);
            *(short8*)(As + p2_pix * 40 + p2_c) = o8;
        }
        __syncthreads();
        short8 af[4], bfm[4];
#pragma unroll
        for (int mi = 0; mi < 4; ++mi)
            af[mi] = *(const short8*)(As + (wr * 64 + mi * 16 + lrow) * 40 + lhk);
#pragma unroll
        for (int ni = 0; ni < 4; ++ni)
            bfm[ni] = *(const short8*)(Bs + (wc * 64 + ni * 16 + lrow) * 40 + lhk);
#pragma unroll
        for (int mi = 0; mi < 4; ++mi)
#pragma unroll
            for (int ni = 0; ni < 4; ++ni)
                acc[mi][ni] = __builtin_amdgcn_mfma_f32_16x16x32_bf16(
                    af[mi], bfm[ni], acc[mi][ni], 0, 0, 0);
        __syncthreads();
    }
    // store Z[n][o][k]: acc row = pixel (k), col = o. 4 consecutive k per lane.
    const int kbase = qbase + wr * 64;
    unsigned short* Zn = Z + (size_t)n * CC * HWD;
#pragma unroll
    for (int ni = 0; ni < 4; ++ni) {
        const int o = n0 + wc * 64 + ni * 16 + lrow;
#pragma unroll
        for (int mi = 0; mi < 4; ++mi) {
            ushort4 v;
            v.x = f2bu(acc[mi][ni][0]);
            v.y = f2bu(acc[mi][ni][1]);
            v.z = f2bu(acc[mi][ni][2]);
            v.w = f2bu(acc[mi][ni][3]);
            *(ushort4*)(Zn + (size_t)o * HWD + kbase + mi * 16 + (hi << 2)) = v;
        }
    }
}

// ---------------- attention: out = x + b + (Z P^T)/rowsum ----------------
// 8 waves, 64-query tile, 4 iters of 256 keys (2x128 sub-tiles), 2 barriers/iter.
__global__ __launch_bounds__(512, 4) void k_attn6(const unsigned short* __restrict__ tp,
                                                  const unsigned short* __restrict__ Z,
                                                  const float* __restrict__ bfu,
                                                  const float* __restrict__ x,
                                                  float* __restrict__ out) {
    constexpr int QST = 264;                       // Q row stride (bf16)
    constexpr int PST = 264;                       // P row stride (256 keys + pad)
    constexpr int QSZ = 64 * QST;
    __shared__ __align__(16) unsigned short SL[QSZ + 64 * PST];  // 67,584 B
    __shared__ float rowsum[64];
    unsigned short* Qs = SL;                       // [64][264]
    unsigned short* P  = SL + QSZ;                 // [64][264]

    const int n = blockIdx.x, q0 = blockIdx.y << 6;   // XCD = n % 8
    const int t = threadIdx.x, lane = t & 63, wave = t >> 6;
    const int lrow = lane & 15, hi = lane >> 4, lhk = hi << 3;
    const f32x4 fz = {0.f, 0.f, 0.f, 0.f};

    const unsigned short* tpn = tp + (size_t)n * HWD * CC;
    const unsigned short* Zn  = Z + (size_t)n * CC * HWD;

    if (t < 64) rowsum[t] = 0.f;
    // stage Q tile: rows q0..q0+63, d 0..255
#pragma unroll
    for (int pass = 0; pass < 4; ++pass) {
        int chunk = (pass << 9) + t;               // 0..2047
        int row = chunk >> 5, co = (chunk & 31) << 3;
        *(short8*)(Qs + row * QST + co) =
            *(const short8*)(tpn + (size_t)(q0 + row) * CC + co);
    }
    __syncthreads();

    f32x4 accF[4][4];                              // rows: o-slice 64, cols: q 64
#pragma unroll
    for (int mi = 0; mi < 4; ++mi)
#pragma unroll
        for (int qj = 0; qj < 4; ++qj) accF[mi][qj] = fz;

    const int kw = wave << 4;                      // wave's 16-key slot per 128-tile
    const int ob = wave << 6;                      // wave's 64-output (o) range

    for (int it = 0; it < 4; ++it) {
        const int kv0 = it << 8;                   // 256-key iter base
        // ---- S = Q K^T / 16 over two 128-key sub-tiles, P = exp(S) ----
        float psum[4][4];
#pragma unroll
        for (int qj = 0; qj < 4; ++qj)
#pragma unroll
            for (int j = 0; j < 4; ++j) psum[qj][j] = 0.f;
#pragma unroll
        for (int kt2 = 0; kt2 < 2; ++kt2) {
            const int krow = kv0 + (kt2 << 7) + kw + lrow;
            f32x4 accA[4];
#pragma unroll
            for (int qj = 0; qj < 4; ++qj) accA[qj] = fz;
#pragma unroll
            for (int kt = 0; kt < 8; ++kt) {
                const int d0 = (kt << 5) + lhk;
                short8 kfr = *(const short8*)(tpn + (size_t)krow * CC + 256 + d0);
#pragma unroll
                for (int qj = 0; qj < 4; ++qj) {
                    short8 qfr = *(const short8*)(Qs + (qj * 16 + lrow) * QST + d0);
                    accA[qj] = __builtin_amdgcn_mfma_f32_16x16x32_bf16(qfr, kfr, accA[qj], 0, 0, 0);
                }
            }
            const int pcol = (kt2 << 7) + kw + lrow;
#pragma unroll
            for (int qj = 0; qj < 4; ++qj)
#pragma unroll
                for (int j = 0; j < 4; ++j) {
                    float p = __expf(accA[qj][j] * 0.0625f);
                    psum[qj][j] += p;
                    P[(qj * 16 + hi * 4 + j) * PST + pcol] = f2bu(p);
                }
        }
        // fold psum into rowsum now (frees registers for ZP phase)
#pragma unroll
        for (int qj = 0; qj < 4; ++qj)
#pragma unroll
            for (int j = 0; j < 4; ++j) {
                float s = psum[qj][j];
                s += __shfl_xor(s, 1, 16);
                s += __shfl_xor(s, 2, 16);
                s += __shfl_xor(s, 4, 16);
                s += __shfl_xor(s, 8, 16);
                if (lrow == 0) atomicAdd(&rowsum[qj * 16 + hi * 4 + j], s);
            }
        __syncthreads();                           // P complete
        // ---- accF += Z . P^T over the 256 keys ----
        __builtin_amdgcn_s_setprio(1);
#pragma unroll
        for (int ks = 0; ks < 8; ++ks) {
            const int kb = (ks << 5) + lhk;
            short8 zf[4];
#pragma unroll
            for (int mi = 0; mi < 4; ++mi)
                zf[mi] = *(const short8*)(Zn + (size_t)(ob + mi * 16 + lrow) * HWD + kv0 + kb);
#pragma unroll
            for (int qj = 0; qj < 4; ++qj) {
                short8 pa = *(const short8*)(P + (qj * 16 + lrow) * PST + kb);
#pragma unroll
                for (int mi = 0; mi < 4; ++mi)
                    accF[mi][qj] = __builtin_amdgcn_mfma_f32_16x16x32_bf16(zf[mi], pa, accF[mi][qj], 0, 0, 0);
            }
        }
        __builtin_amdgcn_s_setprio(0);
        __syncthreads();                           // P consumed; rowsum atomics done
    }

    // ---- epilogue: out[n, o, q] = x + b_fuse[o] + accF / rowsum[q] ----
    float inv[4];
#pragma unroll
    for (int qj = 0; qj < 4; ++qj) inv[qj] = 1.f / rowsum[qj * 16 + lrow];
#pragma unroll
    for (int mi = 0; mi < 4; ++mi) {
#pragma unroll
        for (int j = 0; j < 4; ++j) {
            const int o = ob + mi * 16 + hi * 4 + j;
            const float bias = bfu[o];
#pragma unroll
            for (int qj = 0; qj < 4; ++qj) {
                const int q = q0 + qj * 16 + lrow;
                const size_t idx = ((size_t)(n * CC + o)) * HWD + q;
                out[idx] = accF[mi][qj][j] * inv[qj] + bias + x[idx];
            }
        }
    }
}

extern "C" void kernel_launch(void* const* d_in, const int* in_sizes, int n_in,
                              void* d_out, int out_size, void* d_ws, size_t ws_size,
                              hipStream_t stream) {
    const float* x  = (const float*)d_in[0];
    const float* Wt = (const float*)d_in[1];
    const float* bt = (const float*)d_in[2];
    const float* Wp = (const float*)d_in[3];
    const float* bp = (const float*)d_in[4];
    const float* Wf = (const float*)d_in[5];
    const float* bfu = (const float*)d_in[6];
    float* out = (float*)d_out;

    char* ws = (char*)d_ws;
    unsigned short* tp    = (unsigned short*)(ws);                 // 32 MB
    unsigned short* Z     = (unsigned short*)(ws + 33554432);      // 32 MB
    unsigned short* Wcat  = (unsigned short*)(ws + 67108864);      // 512 KB
    unsigned short* Wfuse = (unsigned short*)(ws + 67633152);      // 512 KB

    k_packw <<<dim3(1024), 256, 0, stream>>>(Wt, Wp, Wf, Wcat, Wfuse);
    k_embed2<<<dim3(256, 2), 512, 0, stream>>>(x, Wcat, bt, bp, tp);
    k_zgemm <<<dim3(256, 2), 512, 0, stream>>>(x, Wfuse, Z);
    k_attn6 <<<dim3(32, 16), 512, 0, stream>>>(tp, Z, bfu, x, out);
}

// Round 7
// 190.564 us; speedup vs baseline: 1.7690x; 1.0251x over previous
//
#include <hip/hip_runtime.h>

// Problem: N=32, C=512, H=W=32 (HW=1024), D=256.
// out = x + b_fuse + (Z P^T)/rowsum ; Z = W_fuse * V, P = exp(Q K^T/16).
//
// Pipeline:
//  k_packw : weights -> bf16
//  k_mm    : merged embed GEMM (tp = [theta|phi]) + Z GEMM, grid (256,4)
//  k_attn7 : per (n, 64-query tile), 8 waves, 1 block/CU (register-heavy):
//            4 iters of 256 keys: S phase (kt-outer, kfr 1-ahead prefetch,
//            accA[2][4]) -> P LDS; ZP phase (zf 2-ahead ring) -> accF.
//            Grid remapped so 16 batches resident (2/XCD -> K,Z L2-resident).
//
// Workspace (65 MB): [0,32MB) tp ; [32,64MB) Z ; [64MB,+512K) Wcat ; [+512K,+1MB) Wfuse

#define NB  32
#define CC  512
#define HWD 1024

typedef __attribute__((ext_vector_type(8))) short short8;
typedef __attribute__((ext_vector_type(4))) float f32x4;

__device__ __forceinline__ unsigned short f2bu(float f) {
    unsigned int u = __float_as_uint(f);
    u = (u + 0x7FFFu + ((u >> 16) & 1u)) >> 16;   // RNE to bf16
    return (unsigned short)u;
}

// ---------------- weights pack ----------------
__global__ __launch_bounds__(256) void k_packw(const float* __restrict__ Wt,
                                               const float* __restrict__ Wp,
                                               const float* __restrict__ Wf,
                                               unsigned short* __restrict__ Wcat,
                                               unsigned short* __restrict__ Wfuse) {
    int idx = blockIdx.x * 256 + threadIdx.x;       // 0 .. 262143
    int o = idx >> 9;
    float cv = (o < 256) ? Wt[idx] : Wp[idx - 131072];
    Wcat[idx]  = f2bu(cv);
    Wfuse[idx] = f2bu(Wf[idx]);
}

// ---------------- merged GEMM: embed (y<2) / Z (y>=2) ----------------
// M-tile 128 pixels (transpose-staged from fp32 x), N-tile 256.
__global__ __launch_bounds__(512) void k_mm(const float* __restrict__ x,
                                            const unsigned short* __restrict__ Wcat,
                                            const unsigned short* __restrict__ Wfuse,
                                            const float* __restrict__ bt,
                                            const float* __restrict__ bp,
                                            unsigned short* __restrict__ tp,
                                            unsigned short* __restrict__ Z) {
    __shared__ __align__(16) float Tr[32 * 132];                 // 16896 B
    __shared__ __align__(16) unsigned short As[128 * 40];        // 10240 B
    __shared__ __align__(16) unsigned short Bs[256 * 40];        // 20480 B
    const int m0 = blockIdx.x << 7;                // global pixel row base
    const int yb = blockIdx.y;
    const bool isZ = (yb >= 2);
    const int n0 = (yb & 1) << 8;                  // col base (0 or 256)
    const unsigned short* W = isZ ? Wfuse : Wcat;
    const int n  = m0 >> 10, qbase = m0 & 1023;
    const int t = threadIdx.x, lane = t & 63, wave = t >> 6;
    const int wr = wave >> 2, wc = wave & 3;
    const int lrow = lane & 15, hi = lane >> 4, lhk = hi << 3;
    const f32x4 fz = {0.f, 0.f, 0.f, 0.f};
    f32x4 acc[4][4];
#pragma unroll
    for (int i = 0; i < 4; ++i)
#pragma unroll
        for (int j = 0; j < 4; ++j) acc[i][j] = fz;

    const int tr_r = t >> 4, tr_q = (t & 15) << 3;        // Tr stage
    const int p2_pix = t & 127, p2_c = (t >> 7) << 3;     // transpose

    for (int kt = 0; kt < 16; ++kt) {
        const int k0 = kt << 5;
        {
            const float* src = x + ((size_t)(n * CC + k0 + tr_r)) * HWD + qbase + tr_q;
            float4 v0 = *(const float4*)(src);
            float4 v1 = *(const float4*)(src + 4);
            *(float4*)(Tr + tr_r * 132 + tr_q) = v0;
            *(float4*)(Tr + tr_r * 132 + tr_q + 4) = v1;
#pragma unroll
            for (int i = 0; i < 2; ++i) {
                int chunk = t + (i << 9);
                int r = chunk >> 2, ko = (chunk & 3) << 3;
                *(uint4*)(Bs + r * 40 + ko) =
                    *(const uint4*)(W + ((size_t)(n0 + r)) * CC + k0 + ko);
            }
        }
        __syncthreads();
        {
            short8 o8;
#pragma unroll
            for (int j = 0; j < 8; ++j)
                o8[j] = (short)f2bu(Tr[(p2_c + j) * 132 + p2_pix]);
            *(short8*)(As + p2_pix * 40 + p2_c) = o8;
        }
        __syncthreads();
        short8 af[4], bfm[4];
#pragma unroll
        for (int mi = 0; mi < 4; ++mi)
            af[mi] = *(const short8*)(As + (wr * 64 + mi * 16 + lrow) * 40 + lhk);
#pragma unroll
        for (int ni = 0; ni < 4; ++ni)
            bfm[ni] = *(const short8*)(Bs + (wc * 64 + ni * 16 + lrow) * 40 + lhk);
#pragma unroll
        for (int mi = 0; mi < 4; ++mi)
#pragma unroll
            for (int ni = 0; ni < 4; ++ni)
                acc[mi][ni] = __builtin_amdgcn_mfma_f32_16x16x32_bf16(
                    af[mi], bfm[ni], acc[mi][ni], 0, 0, 0);
        __syncthreads();
    }
    if (!isZ) {
#pragma unroll
        for (int ni = 0; ni < 4; ++ni) {
            const int col = n0 + wc * 64 + ni * 16 + lrow;
            const float bias = (col < 256) ? bt[col] : bp[col - 256];
#pragma unroll
            for (int mi = 0; mi < 4; ++mi)
#pragma unroll
                for (int j = 0; j < 4; ++j) {
                    const int row = m0 + wr * 64 + mi * 16 + hi * 4 + j;
                    tp[(size_t)row * CC + col] = f2bu(acc[mi][ni][j] + bias);
                }
        }
    } else {
        const int kbase = qbase + wr * 64;
        unsigned short* Zn = Z + (size_t)n * CC * HWD;
#pragma unroll
        for (int ni = 0; ni < 4; ++ni) {
            const int o = n0 + wc * 64 + ni * 16 + lrow;
#pragma unroll
            for (int mi = 0; mi < 4; ++mi) {
                ushort4 v;
                v.x = f2bu(acc[mi][ni][0]);
                v.y = f2bu(acc[mi][ni][1]);
                v.z = f2bu(acc[mi][ni][2]);
                v.w = f2bu(acc[mi][ni][3]);
                *(ushort4*)(Zn + (size_t)o * HWD + kbase + mi * 16 + (hi << 2)) = v;
            }
        }
    }
}

// ---------------- attention: out = x + b + (Z P^T)/rowsum ----------------
// 8 waves, 64-query tile, 4 iters of 256 keys, 1 block/CU, register-prefetched.
__global__ __launch_bounds__(512, 2) void k_attn7(const unsigned short* __restrict__ tp,
                                                  const unsigned short* __restrict__ Z,
                                                  const float* __restrict__ bfu,
                                                  const float* __restrict__ x,
                                                  float* __restrict__ out) {
    constexpr int QST = 264;
    constexpr int PST = 264;
    constexpr int QSZ = 64 * QST;
    __shared__ __align__(16) unsigned short SL[QSZ + 64 * PST];  // 67,584 B
    __shared__ float rowsum[64];
    unsigned short* Qs = SL;
    unsigned short* P  = SL + QSZ;

    // remap: round r = b>>8 (0,1); n = (b&15) + 16r -> 16 batches resident (2/XCD)
    const int b = blockIdx.x;
    const int n = (b & 15) | ((b >> 8) << 4);
    const int q0 = ((b >> 4) & 15) << 6;
    const int t = threadIdx.x, lane = t & 63, wave = t >> 6;
    const int lrow = lane & 15, hi = lane >> 4, lhk = hi << 3;
    const f32x4 fz = {0.f, 0.f, 0.f, 0.f};

    const unsigned short* tpn = tp + (size_t)n * HWD * CC;
    const unsigned short* Zn  = Z + (size_t)n * CC * HWD;

    if (t < 64) rowsum[t] = 0.f;
#pragma unroll
    for (int pass = 0; pass < 4; ++pass) {
        int chunk = (pass << 9) + t;
        int row = chunk >> 5, co = (chunk & 31) << 3;
        *(short8*)(Qs + row * QST + co) =
            *(const short8*)(tpn + (size_t)(q0 + row) * CC + co);
    }
    __syncthreads();

    f32x4 accF[4][4];
#pragma unroll
    for (int mi = 0; mi < 4; ++mi)
#pragma unroll
        for (int qj = 0; qj < 4; ++qj) accF[mi][qj] = fz;
    float psum[4][4];
#pragma unroll
    for (int qj = 0; qj < 4; ++qj)
#pragma unroll
        for (int j = 0; j < 4; ++j) psum[qj][j] = 0.f;

    const int kw = wave << 4;
    const int ob = wave << 6;

    for (int it = 0; it < 4; ++it) {
        const int kv0 = it << 8;
        const size_t krow0 = (size_t)(kv0 + kw + lrow) * CC + 256;
        const size_t krow1 = (size_t)(kv0 + 128 + kw + lrow) * CC + 256;
        // ---- S phase: kt-outer, kfr 1-ahead prefetch ----
        f32x4 accA[2][4];
#pragma unroll
        for (int k2 = 0; k2 < 2; ++k2)
#pragma unroll
            for (int qj = 0; qj < 4; ++qj) accA[k2][qj] = fz;
        short8 kpre[2][2];
        kpre[0][0] = *(const short8*)(tpn + krow0 + lhk);
        kpre[0][1] = *(const short8*)(tpn + krow1 + lhk);
#pragma unroll
        for (int kt = 0; kt < 8; ++kt) {
            const int d0 = (kt << 5) + lhk;
            if (kt < 7) {
                const int dn = ((kt + 1) << 5) + lhk;
                kpre[(kt + 1) & 1][0] = *(const short8*)(tpn + krow0 + dn);
                kpre[(kt + 1) & 1][1] = *(const short8*)(tpn + krow1 + dn);
            }
            short8 qfr[4];
#pragma unroll
            for (int qj = 0; qj < 4; ++qj)
                qfr[qj] = *(const short8*)(Qs + (qj * 16 + lrow) * QST + d0);
            __builtin_amdgcn_s_setprio(1);
#pragma unroll
            for (int k2 = 0; k2 < 2; ++k2)
#pragma unroll
                for (int qj = 0; qj < 4; ++qj)
                    accA[k2][qj] = __builtin_amdgcn_mfma_f32_16x16x32_bf16(
                        qfr[qj], kpre[kt & 1][k2], accA[k2][qj], 0, 0, 0);
            __builtin_amdgcn_s_setprio(0);
        }
#pragma unroll
        for (int k2 = 0; k2 < 2; ++k2) {
            const int pcol = (k2 << 7) + kw + lrow;
#pragma unroll
            for (int qj = 0; qj < 4; ++qj)
#pragma unroll
                for (int j = 0; j < 4; ++j) {
                    float p = __expf(accA[k2][qj][j] * 0.0625f);
                    psum[qj][j] += p;
                    P[(qj * 16 + hi * 4 + j) * PST + pcol] = f2bu(p);
                }
        }
        __syncthreads();                           // P complete
        // ---- ZP phase: zf 2-ahead ring (3 buffers) ----
        short8 zfr[3][4];
#pragma unroll
        for (int s = 0; s < 2; ++s)
#pragma unroll
            for (int mi = 0; mi < 4; ++mi)
                zfr[s][mi] = *(const short8*)(Zn + (size_t)(ob + mi * 16 + lrow) * HWD +
                                              kv0 + (s << 5) + lhk);
        __builtin_amdgcn_s_setprio(1);
#pragma unroll
        for (int ks = 0; ks < 8; ++ks) {
            const int kb = (ks << 5) + lhk;
            if (ks < 6) {
#pragma unroll
                for (int mi = 0; mi < 4; ++mi)
                    zfr[(ks + 2) % 3][mi] =
                        *(const short8*)(Zn + (size_t)(ob + mi * 16 + lrow) * HWD +
                                         kv0 + ((ks + 2) << 5) + lhk);
            }
#pragma unroll
            for (int qj = 0; qj < 4; ++qj) {
                short8 pa = *(const short8*)(P + (qj * 16 + lrow) * PST + kb);
#pragma unroll
                for (int mi = 0; mi < 4; ++mi)
                    accF[mi][qj] = __builtin_amdgcn_mfma_f32_16x16x32_bf16(
                        zfr[ks % 3][mi], pa, accF[mi][qj], 0, 0, 0);
            }
        }
        __builtin_amdgcn_s_setprio(0);
        __syncthreads();                           // P consumed
    }

    // ---- fold psum -> rowsum ----
#pragma unroll
    for (int qj = 0; qj < 4; ++qj)
#pragma unroll
        for (int j = 0; j < 4; ++j) {
            float s = psum[qj][j];
            s += __shfl_xor(s, 1, 16);
            s += __shfl_xor(s, 2, 16);
            s += __shfl_xor(s, 4, 16);
            s += __shfl_xor(s, 8, 16);
            if (lrow == 0) atomicAdd(&rowsum[qj * 16 + hi * 4 + j], s);
        }
    __syncthreads();

    // ---- epilogue: out[n, o, q] = x + b_fuse[o] + accF / rowsum[q] ----
    float inv[4];
#pragma unroll
    for (int qj = 0; qj < 4; ++qj) inv[qj] = 1.f / rowsum[qj * 16 + lrow];
#pragma unroll
    for (int mi = 0; mi < 4; ++mi) {
#pragma unroll
        for (int j = 0; j < 4; ++j) {
            const int o = ob + mi * 16 + hi * 4 + j;
            const float bias = bfu[o];
#pragma unroll
            for (int qj = 0; qj < 4; ++qj) {
                const int q = q0 + qj * 16 + lrow;
                const size_t idx = ((size_t)(n * CC + o)) * HWD + q;
                out[idx] = accF[mi][qj][j] * inv[qj] + bias + x[idx];
            }
        }
    }
}

extern "C" void kernel_launch(void* const* d_in, const int* in_sizes, int n_in,
                              void* d_out, int out_size, void* d_ws, size_t ws_size,
                              hipStream_t stream) {
    const float* x  = (const float*)d_in[0];
    const float* Wt = (const float*)d_in[1];
    const float* bt = (const float*)d_in[2];
    const float* Wp = (const float*)d_in[3];
    const float* bp = (const float*)d_in[4];
    const float* Wf = (const float*)d_in[5];
    const float* bfu = (const float*)d_in[6];
    float* out = (float*)d_out;

    char* ws = (char*)d_ws;
    unsigned short* tp    = (unsigned short*)(ws);                 // 32 MB
    unsigned short* Z     = (unsigned short*)(ws + 33554432);      // 32 MB
    unsigned short* Wcat  = (unsigned short*)(ws + 67108864);      // 512 KB
    unsigned short* Wfuse = (unsigned short*)(ws + 67633152);      // 512 KB

    k_packw<<<dim3(1024), 256, 0, stream>>>(Wt, Wp, Wf, Wcat, Wfuse);
    k_mm   <<<dim3(256, 4), 512, 0, stream>>>(x, Wcat, Wfuse, bt, bp, tp, Z);
    k_attn7<<<dim3(512), 512, 0, stream>>>(tp, Z, bfu, x, out);
}

// Round 8
// 170.511 us; speedup vs baseline: 1.9771x; 1.1176x over previous
//
#include <hip/hip_runtime.h>

// Problem: N=32, C=512, H=W=32 (HW=1024), D=256.
// out = x + b_fuse + (Z P^T)/rowsum ; Z = W_fuse * V, P = exp(Q K^T/16).
//
// Pipeline:
//  k_packw : weights -> bf16
//  k_mm    : merged embed GEMM (tp = [theta|phi]) + Z GEMM, grid (256,4)
//  k_attn8 : per (n, 128-query tile), 8 waves, 256 blocks (exactly 1/CU).
//            4 iters of 256 keys: S phase (both 128-key subtiles per pass,
//            kfr pair loaded once per kt, qfr reused x2, accA[2][8]) -> P LDS
//            [128][264]; ZP phase swapped-operand mfma(pa, zf) -> accG[8][4]
//            (q-major output -> float4 stores + residual loads).
//            q-tile 128 halves device-wide K/Z gather traffic vs q64.
//
// Workspace (65 MB): [0,32MB) tp ; [32,64MB) Z ; [64MB,+512K) Wcat ; [+512K,+1MB) Wfuse

#define NB  32
#define CC  512
#define HWD 1024

typedef __attribute__((ext_vector_type(8))) short short8;
typedef __attribute__((ext_vector_type(4))) float f32x4;

__device__ __forceinline__ unsigned short f2bu(float f) {
    unsigned int u = __float_as_uint(f);
    u = (u + 0x7FFFu + ((u >> 16) & 1u)) >> 16;   // RNE to bf16
    return (unsigned short)u;
}

// ---------------- weights pack ----------------
__global__ __launch_bounds__(256) void k_packw(const float* __restrict__ Wt,
                                               const float* __restrict__ Wp,
                                               const float* __restrict__ Wf,
                                               unsigned short* __restrict__ Wcat,
                                               unsigned short* __restrict__ Wfuse) {
    int idx = blockIdx.x * 256 + threadIdx.x;       // 0 .. 262143
    int o = idx >> 9;
    float cv = (o < 256) ? Wt[idx] : Wp[idx - 131072];
    Wcat[idx]  = f2bu(cv);
    Wfuse[idx] = f2bu(Wf[idx]);
}

// ---------------- merged GEMM: embed (y<2) / Z (y>=2) ----------------
// M-tile 128 pixels (transpose-staged from fp32 x), N-tile 256.
__global__ __launch_bounds__(512) void k_mm(const float* __restrict__ x,
                                            const unsigned short* __restrict__ Wcat,
                                            const unsigned short* __restrict__ Wfuse,
                                            const float* __restrict__ bt,
                                            const float* __restrict__ bp,
                                            unsigned short* __restrict__ tp,
                                            unsigned short* __restrict__ Z) {
    __shared__ __align__(16) float Tr[32 * 132];                 // 16896 B
    __shared__ __align__(16) unsigned short As[128 * 40];        // 10240 B
    __shared__ __align__(16) unsigned short Bs[256 * 40];        // 20480 B
    const int m0 = blockIdx.x << 7;                // global pixel row base
    const int yb = blockIdx.y;
    const bool isZ = (yb >= 2);
    const int n0 = (yb & 1) << 8;                  // col base (0 or 256)
    const unsigned short* W = isZ ? Wfuse : Wcat;
    const int n  = m0 >> 10, qbase = m0 & 1023;
    const int t = threadIdx.x, lane = t & 63, wave = t >> 6;
    const int wr = wave >> 2, wc = wave & 3;
    const int lrow = lane & 15, hi = lane >> 4, lhk = hi << 3;
    const f32x4 fz = {0.f, 0.f, 0.f, 0.f};
    f32x4 acc[4][4];
#pragma unroll
    for (int i = 0; i < 4; ++i)
#pragma unroll
        for (int j = 0; j < 4; ++j) acc[i][j] = fz;

    const int tr_r = t >> 4, tr_q = (t & 15) << 3;        // Tr stage
    const int p2_pix = t & 127, p2_c = (t >> 7) << 3;     // transpose

    for (int kt = 0; kt < 16; ++kt) {
        const int k0 = kt << 5;
        {
            const float* src = x + ((size_t)(n * CC + k0 + tr_r)) * HWD + qbase + tr_q;
            float4 v0 = *(const float4*)(src);
            float4 v1 = *(const float4*)(src + 4);
            *(float4*)(Tr + tr_r * 132 + tr_q) = v0;
            *(float4*)(Tr + tr_r * 132 + tr_q + 4) = v1;
#pragma unroll
            for (int i = 0; i < 2; ++i) {
                int chunk = t + (i << 9);
                int r = chunk >> 2, ko = (chunk & 3) << 3;
                *(uint4*)(Bs + r * 40 + ko) =
                    *(const uint4*)(W + ((size_t)(n0 + r)) * CC + k0 + ko);
            }
        }
        __syncthreads();
        {
            short8 o8;
#pragma unroll
            for (int j = 0; j < 8; ++j)
                o8[j] = (short)f2bu(Tr[(p2_c + j) * 132 + p2_pix]);
            *(short8*)(As + p2_pix * 40 + p2_c) = o8;
        }
        __syncthreads();
        short8 af[4], bfm[4];
#pragma unroll
        for (int mi = 0; mi < 4; ++mi)
            af[mi] = *(const short8*)(As + (wr * 64 + mi * 16 + lrow) * 40 + lhk);
#pragma unroll
        for (int ni = 0; ni < 4; ++ni)
            bfm[ni] = *(const short8*)(Bs + (wc * 64 + ni * 16 + lrow) * 40 + lhk);
#pragma unroll
        for (int mi = 0; mi < 4; ++mi)
#pragma unroll
            for (int ni = 0; ni < 4; ++ni)
                acc[mi][ni] = __builtin_amdgcn_mfma_f32_16x16x32_bf16(
                    af[mi], bfm[ni], acc[mi][ni], 0, 0, 0);
        __syncthreads();
    }
    if (!isZ) {
#pragma unroll
        for (int ni = 0; ni < 4; ++ni) {
            const int col = n0 + wc * 64 + ni * 16 + lrow;
            const float bias = (col < 256) ? bt[col] : bp[col - 256];
#pragma unroll
            for (int mi = 0; mi < 4; ++mi)
#pragma unroll
                for (int j = 0; j < 4; ++j) {
                    const int row = m0 + wr * 64 + mi * 16 + hi * 4 + j;
                    tp[(size_t)row * CC + col] = f2bu(acc[mi][ni][j] + bias);
                }
        }
    } else {
        const int kbase = qbase + wr * 64;
        unsigned short* Zn = Z + (size_t)n * CC * HWD;
#pragma unroll
        for (int ni = 0; ni < 4; ++ni) {
            const int o = n0 + wc * 64 + ni * 16 + lrow;
#pragma unroll
            for (int mi = 0; mi < 4; ++mi) {
                ushort4 v;
                v.x = f2bu(acc[mi][ni][0]);
                v.y = f2bu(acc[mi][ni][1]);
                v.z = f2bu(acc[mi][ni][2]);
                v.w = f2bu(acc[mi][ni][3]);
                *(ushort4*)(Zn + (size_t)o * HWD + kbase + mi * 16 + (hi << 2)) = v;
            }
        }
    }
}

// ---------------- attention: out = x + b + (Z P^T)/rowsum ----------------
// 8 waves, 128-query tile, 4 iters of 256 keys, 256 blocks = 1/CU.
__global__ __launch_bounds__(512, 2) void k_attn8(const unsigned short* __restrict__ tp,
                                                  const unsigned short* __restrict__ Z,
                                                  const float* __restrict__ bfu,
                                                  const float* __restrict__ x,
                                                  float* __restrict__ out) {
    constexpr int QST = 264;
    constexpr int PST = 264;
    constexpr int QSZ = 128 * QST;
    __shared__ __align__(16) unsigned short SL[QSZ + 128 * PST];  // 135,168 B
    __shared__ float rowsum[128];
    unsigned short* Qs = SL;                       // [128][264]
    unsigned short* P  = SL + QSZ;                 // [128][264] (256 keys + pad)

    const int b = blockIdx.x;
    const int n = b & 31;                          // XCD = b%8 = n%8 -> 4 batches/XCD
    const int q0 = (b >> 5) << 7;                  // 8 q-tiles of 128
    const int t = threadIdx.x, lane = t & 63, wave = t >> 6;
    const int lrow = lane & 15, hi = lane >> 4, lhk = hi << 3;
    const f32x4 fz = {0.f, 0.f, 0.f, 0.f};

    const unsigned short* tpn = tp + (size_t)n * HWD * CC;
    const unsigned short* Zn  = Z + (size_t)n * CC * HWD;

    if (t < 128) rowsum[t] = 0.f;
    // stage Q tile: rows q0..q0+127, d 0..255 (coalesced row-major)
#pragma unroll
    for (int pass = 0; pass < 8; ++pass) {
        int chunk = (pass << 9) + t;               // 0..4095
        int row = chunk >> 5, co = (chunk & 31) << 3;
        *(short8*)(Qs + row * QST + co) =
            *(const short8*)(tpn + (size_t)(q0 + row) * CC + co);
    }
    __syncthreads();

    f32x4 accG[8][4];                              // [qj][mi]: row=q, col=o
#pragma unroll
    for (int qj = 0; qj < 8; ++qj)
#pragma unroll
        for (int mi = 0; mi < 4; ++mi) accG[qj][mi] = fz;

    const int kw = wave << 4;                      // wave's 16-key slot per 128-sub
    const int ob = wave << 6;                      // wave's 64-output (o) range

    for (int it = 0; it < 4; ++it) {
        const int kv0 = it << 8;                   // 256-key iter base
        const size_t krow0 = (size_t)(kv0 + kw + lrow) * CC + 256;
        const size_t krow1 = (size_t)(kv0 + 128 + kw + lrow) * CC + 256;
        // ---- S phase: both 128-key subtiles, kfr pair loaded once per kt ----
        f32x4 accA[2][8];
#pragma unroll
        for (int k2 = 0; k2 < 2; ++k2)
#pragma unroll
            for (int qj = 0; qj < 8; ++qj) accA[k2][qj] = fz;
#pragma unroll
        for (int kt = 0; kt < 8; ++kt) {
            const int d0 = (kt << 5) + lhk;
            short8 kf0 = *(const short8*)(tpn + krow0 + d0);
            short8 kf1 = *(const short8*)(tpn + krow1 + d0);
#pragma unroll
            for (int qj = 0; qj < 8; ++qj) {
                short8 qfr = *(const short8*)(Qs + (qj * 16 + lrow) * QST + d0);
                accA[0][qj] = __builtin_amdgcn_mfma_f32_16x16x32_bf16(qfr, kf0, accA[0][qj], 0, 0, 0);
                accA[1][qj] = __builtin_amdgcn_mfma_f32_16x16x32_bf16(qfr, kf1, accA[1][qj], 0, 0, 0);
            }
        }
        // exp -> P, psum -> rowsum
        float psum[8][4];
#pragma unroll
        for (int qj = 0; qj < 8; ++qj)
#pragma unroll
            for (int j = 0; j < 4; ++j) psum[qj][j] = 0.f;
#pragma unroll
        for (int k2 = 0; k2 < 2; ++k2) {
            const int pcol = (k2 << 7) + kw + lrow;
#pragma unroll
            for (int qj = 0; qj < 8; ++qj)
#pragma unroll
                for (int j = 0; j < 4; ++j) {
                    float p = __expf(accA[k2][qj][j] * 0.0625f);
                    psum[qj][j] += p;
                    P[(qj * 16 + hi * 4 + j) * PST + pcol] = f2bu(p);
                }
        }
#pragma unroll
        for (int qj = 0; qj < 8; ++qj)
#pragma unroll
            for (int j = 0; j < 4; ++j) {
                float s = psum[qj][j];
                s += __shfl_xor(s, 1, 16);
                s += __shfl_xor(s, 2, 16);
                s += __shfl_xor(s, 4, 16);
                s += __shfl_xor(s, 8, 16);
                if (lrow == 0) atomicAdd(&rowsum[qj * 16 + hi * 4 + j], s);
            }
        __syncthreads();                           // P complete
        // ---- ZP phase: accG[q][o] += P . Z^T (swapped operands) ----
        __builtin_amdgcn_s_setprio(1);
#pragma unroll
        for (int ks = 0; ks < 8; ++ks) {
            const int kb = (ks << 5) + lhk;
            short8 zf[4];
#pragma unroll
            for (int mi = 0; mi < 4; ++mi)
                zf[mi] = *(const short8*)(Zn + (size_t)(ob + mi * 16 + lrow) * HWD + kv0 + kb);
#pragma unroll
            for (int qj = 0; qj < 8; ++qj) {
                short8 pa = *(const short8*)(P + (qj * 16 + lrow) * PST + kb);
#pragma unroll
                for (int mi = 0; mi < 4; ++mi)
                    accG[qj][mi] = __builtin_amdgcn_mfma_f32_16x16x32_bf16(
                        pa, zf[mi], accG[qj][mi], 0, 0, 0);
            }
        }
        __builtin_amdgcn_s_setprio(0);
        __syncthreads();                           // P consumed; atomics drained
    }

    // ---- epilogue: out[n, o, q] = x + b_fuse[o] + accG / rowsum[q] ----
    if (t < 128) rowsum[t] = 1.f / rowsum[t];
    __syncthreads();
    float bias[4];
#pragma unroll
    for (int mi = 0; mi < 4; ++mi) bias[mi] = bfu[ob + mi * 16 + lrow];
#pragma unroll
    for (int qj = 0; qj < 8; ++qj) {
        const float4 inv4 = *(const float4*)&rowsum[qj * 16 + (hi << 2)];
#pragma unroll
        for (int mi = 0; mi < 4; ++mi) {
            const int o = ob + mi * 16 + lrow;
            const size_t idx = ((size_t)(n * CC + o)) * HWD + q0 + qj * 16 + (hi << 2);
            const float4 xr = *(const float4*)(x + idx);
            float4 r;
            r.x = accG[qj][mi][0] * inv4.x + bias[mi] + xr.x;
            r.y = accG[qj][mi][1] * inv4.y + bias[mi] + xr.y;
            r.z = accG[qj][mi][2] * inv4.z + bias[mi] + xr.z;
            r.w = accG[qj][mi][3] * inv4.w + bias[mi] + xr.w;
            *(float4*)(out + idx) = r;
        }
    }
}

extern "C" void kernel_launch(void* const* d_in, const int* in_sizes, int n_in,
                              void* d_out, int out_size, void* d_ws, size_t ws_size,
                              hipStream_t stream) {
    const float* x  = (const float*)d_in[0];
    const float* Wt = (const float*)d_in[1];
    const float* bt = (const float*)d_in[2];
    const float* Wp = (const float*)d_in[3];
    const float* bp = (const float*)d_in[4];
    const float* Wf = (const float*)d_in[5];
    const float* bfu = (const float*)d_in[6];
    float* out = (float*)d_out;

    char* ws = (char*)d_ws;
    unsigned short* tp    = (unsigned short*)(ws);                 // 32 MB
    unsigned short* Z     = (unsigned short*)(ws + 33554432);      // 32 MB
    unsigned short* Wcat  = (unsigned short*)(ws + 67108864);      // 512 KB
    unsigned short* Wfuse = (unsigned short*)(ws + 67633152);      // 512 KB

    k_packw<<<dim3(1024), 256, 0, stream>>>(Wt, Wp, Wf, Wcat, Wfuse);
    k_mm   <<<dim3(256, 4), 512, 0, stream>>>(x, Wcat, Wfuse, bt, bp, tp, Z);
    k_attn8<<<dim3(256), 512, 0, stream>>>(tp, Z, bfu, x, out);
}